// Round 6
// baseline (177.400 us; speedup 1.0000x reference)
//
#include <hip/hip_runtime.h>
#include <stdint.h>

#define N_ROWS 4096
#define D_DIM  1024
#define KBYTES 2048   // bytes per row in bf16
#define T_TEMP 0.15f

#define AS1 __attribute__((address_space(1)))
#define AS3 __attribute__((address_space(3)))

typedef float  f32x16 __attribute__((ext_vector_type(16)));
typedef __bf16 bf16x8 __attribute__((ext_vector_type(8)));

__device__ __forceinline__ unsigned int f2bf(float f) {
  unsigned u = __float_as_uint(f);
  u += 0x7FFF + ((u >> 16) & 1);   // RNE
  return u >> 16;
}

__device__ __forceinline__ float wsum(float v) {
#pragma unroll
  for (int m = 32; m >= 1; m >>= 1) v += __shfl_xor(v, m, 64);
  return v;
}
__device__ __forceinline__ float wmax(float v) {
#pragma unroll
  for (int m = 32; m >= 1; m >>= 1) v = fmaxf(v, __shfl_xor(v, m, 64));
  return v;
}

// One WAVE per row (no barriers): norms, x.y dot (-> log pos), softmax-JS
// per-row term -> js[row], bf16 casts into Bb = [x;y]. Zeroes rowsum.
__global__ __launch_bounds__(256) void prep_kernel(
    const float* __restrict__ x, const float* __restrict__ y,
    unsigned short* __restrict__ Bb, float* __restrict__ inv_n,
    float* __restrict__ logpos, float* __restrict__ js,
    float* __restrict__ rowsum) {
  if (threadIdx.x < 4) rowsum[blockIdx.x * 4 + threadIdx.x] = 0.0f;

  const int wid = threadIdx.x >> 6, lane = threadIdx.x & 63;
  const int row = blockIdx.x * 4 + wid;
  const float4* xp = (const float4*)(x + (size_t)row * D_DIM) + lane * 4;
  const float4* yp = (const float4*)(y + (size_t)row * D_DIM) + lane * 4;

  float xv[16], yv[16];
#pragma unroll
  for (int i = 0; i < 4; ++i) {
    float4 a = xp[i], b = yp[i];
    xv[i*4+0]=a.x; xv[i*4+1]=a.y; xv[i*4+2]=a.z; xv[i*4+3]=a.w;
    yv[i*4+0]=b.x; yv[i*4+1]=b.y; yv[i*4+2]=b.z; yv[i*4+3]=b.w;
  }

  float sx2=0.f, sy2=0.f, sxy=0.f, mx=-1e30f, my=-1e30f;
#pragma unroll
  for (int k = 0; k < 16; ++k) {
    sx2 = fmaf(xv[k], xv[k], sx2);
    sy2 = fmaf(yv[k], yv[k], sy2);
    sxy = fmaf(xv[k], yv[k], sxy);
    mx = fmaxf(mx, xv[k]); my = fmaxf(my, yv[k]);
  }
  sx2 = wsum(sx2); sy2 = wsum(sy2); sxy = wsum(sxy);
  mx = wmax(mx);  my = wmax(my);

  float ex[16], ey[16], sex=0.f, sey=0.f;
#pragma unroll
  for (int k = 0; k < 16; ++k) {
    ex[k] = __expf(xv[k] - mx); ey[k] = __expf(yv[k] - my);
    sex += ex[k]; sey += ey[k];
  }
  sex = wsum(sex); sey = wsum(sey);
  const float lsex = __logf(sex), lsey = __logf(sey);
  const float rsex = 1.f / sex,  rsey = 1.f / sey;

  float term = 0.f;
#pragma unroll
  for (int k = 0; k < 16; ++k) {
    float a = ex[k] * rsex, b = ey[k] * rsey;
    float lm = __logf(0.5f * (a + b));
    term += a * ((xv[k] - mx - lsex) - lm) + b * ((yv[k] - my - lsey) - lm);
  }
  term = wsum(term);

  if (lane == 0) {
    const float nx = sqrtf(sx2), ny = sqrtf(sy2);
    inv_n[row] = 1.f / nx;
    inv_n[N_ROWS + row] = 1.f / ny;
    logpos[row] = sxy / fmaxf(nx * ny, 1e-8f) / T_TEMP;  // ln(pos)
    js[row] = term;
  }

  int p[8], q[8];
#pragma unroll
  for (int w = 0; w < 8; ++w) {
    p[w] = f2bf(xv[2*w]) | (f2bf(xv[2*w+1]) << 16);
    q[w] = f2bf(yv[2*w]) | (f2bf(yv[2*w+1]) << 16);
  }
  int4* ox = (int4*)(Bb + (size_t)row * D_DIM + lane * 16);
  int4* oy = (int4*)(Bb + (size_t)(N_ROWS + row) * D_DIM + lane * 16);
  ox[0] = make_int4(p[0], p[1], p[2], p[3]);
  ox[1] = make_int4(p[4], p[5], p[6], p[7]);
  oy[0] = make_int4(q[0], q[1], q[2], q[3]);
  oy[1] = make_int4(q[4], q[5], q[6], q[7]);
}

// ===== 8-wave 256x256 GEMM, 32x32x16 MFMA, block-linear LDS =====
// LDS = 1KB "fragment blocks": block (s,g) = k-step s (K=16) of 32-row
// group g; element (row, kchunk c) at byte c*512 + row*16 == lane*16.
// Every ds_read_b128 and every global_load_lds is wave-dense contiguous
// 1KB at base + lane*16 (the pattern measured conflict-free in R1-R4).
// Uniform phases: 6 ds_read + 2 GLL + 8 MFMA + vmcnt(6); never vmcnt(0)
// in the main loop (pairs drain with 3 phases of lead).
#define GLL(src, dst) __builtin_amdgcn_global_load_lds((const AS1 void*)(src), (AS3 void*)(dst), 16, 0, 0)
#define STG(s, nb) do { \
  GLL(gAk + (s)*32, dA + (nb)*32768 + (s)*8192); \
  GLL(gBk + (s)*32, dB + (nb)*32768 + (s)*8192); } while(0)
#define RD(s, bf) do { _Pragma("unroll") \
  for (int mt_ = 0; mt_ < 4; ++mt_) \
    a[mt_] = *(const bf16x8*)(laneA + (bf)*32768 + (s)*8192 + mt_*1024); \
  b[0] = *(const bf16x8*)(laneB + (bf)*32768 + (s)*8192); \
  b[1] = *(const bf16x8*)(laneB + (bf)*32768 + (s)*8192 + 1024); } while(0)
#define MM8 do { _Pragma("unroll") \
  for (int mt_ = 0; mt_ < 4; ++mt_) { \
    acc[mt_][0] = __builtin_amdgcn_mfma_f32_32x32x16_bf16(a[mt_], b[0], acc[mt_][0], 0, 0, 0); \
    acc[mt_][1] = __builtin_amdgcn_mfma_f32_32x32x16_bf16(a[mt_], b[1], acc[mt_][1], 0, 0, 0); } } while(0)
#define BARR  __builtin_amdgcn_s_barrier()
#define LGKM0 asm volatile("s_waitcnt lgkmcnt(0)")
#define VM6   asm volatile("s_waitcnt vmcnt(6)" ::: "memory")
#define VM4   asm volatile("s_waitcnt vmcnt(4)" ::: "memory")
#define VM2   asm volatile("s_waitcnt vmcnt(2)" ::: "memory")
#define VM0   asm volatile("s_waitcnt vmcnt(0)" ::: "memory")
#define PR1   __builtin_amdgcn_s_setprio(1)
#define PR0   __builtin_amdgcn_s_setprio(0)
// steady-state phase: read k-step s of buf bf, stage k-step s of next tile
#define PH(s, bf) do { RD(s, bf); STG(s, (bf)^1); \
  BARR; LGKM0; PR1; MM8; PR0; VM6; BARR; } while(0)
// tail phase: no staging, custom drain
#define PHT(s, bf, DRAIN) do { RD(s, bf); \
  BARR; LGKM0; PR1; MM8; PR0; DRAIN; BARR; } while(0)

__global__ __launch_bounds__(512, 2) void gemm_fused(
    const unsigned short* __restrict__ Bb, const float* __restrict__ inv_n,
    float* __restrict__ rowsum) {
  __shared__ __align__(16) char As[2 * 32768];
  __shared__ __align__(16) char Bs[2 * 32768];
  const int tid = threadIdx.x;
  const int wid = tid >> 6, lane = tid & 63;
  const int l31 = lane & 31, l5 = lane >> 5;
  const int wm = wid >> 2, wn = wid & 3;

  // chunked XCD swizzle: 512 blocks -> 8 XCD chunks of 8x8 tile blocks
  const int id = blockIdx.x;
  const int u = (id & 7) * 64 + (id >> 3);
  const int ch = u >> 6, lcl = u & 63;
  const int bx = ((ch & 1) << 3) + (lcl >> 3);
  const int by = ((ch >> 1) << 3) + (lcl & 7);
  const int grow0 = bx * 256, gcol0 = by * 256;

  f32x16 acc[4][2] = {};
  bf16x8 a[4], b[2];

  // staging sources: wave w owns row-group g = w; lane l fetches
  // (row = g*32 + (l&31), kchunk c = l>>5) -> lands at LDS lane*16.
  const char* gA = (const char*)Bb + (size_t)(grow0 + wid * 32 + l31) * KBYTES + l5 * 16;
  const char* gB = (const char*)Bb + (size_t)(gcol0 + wid * 32 + l31) * KBYTES + l5 * 16;
  char* dA = As + wid * 1024;   // + nb*32768 + s*8192
  char* dB = Bs + wid * 1024;

  // fragment-read bases: block (s, g): A g = wm*4+mt, B g = wn*2+n
  const char* laneA = As + wm * 4096 + lane * 16;
  const char* laneB = Bs + wn * 2048 + lane * 16;

  // prologue: stage tile 0 into buf 0 (order s0A,s0B,s1A,s1B,...)
  {
    const char* gAk = gA; const char* gBk = gB;
    STG(0, 0); STG(1, 0); STG(2, 0); STG(3, 0);
  }
  VM6;   // t0:s0 pair complete
  BARR;

  for (int kt = 0; kt < 14; kt += 2) {
    { const char* gAk = gA + (kt + 1) * 128; const char* gBk = gB + (kt + 1) * 128;
      PH(0, 0); PH(1, 0); PH(2, 0); PH(3, 0); }
    { const char* gAk = gA + (kt + 2) * 128; const char* gBk = gB + (kt + 2) * 128;
      PH(0, 1); PH(1, 1); PH(2, 1); PH(3, 1); }
  }
  { const char* gAk = gA + 15 * 128; const char* gBk = gB + 15 * 128;
    PH(0, 0); PH(1, 0); PH(2, 0); PH(3, 0); }
  // tail tile 15 (buf 1): drains 4 -> 2 -> 0
  PHT(0, 1, VM4);
  PHT(1, 1, VM2);
  PHT(2, 1, VM0);
  PHT(3, 1, (void)0);

  // ===== epilogue (32x32 C/D layout: col=l31, row=(r&3)+8*(r>>2)+4*l5) =====
  const float C = 1.4426950408889634f / T_TEMP;   // log2(e)/T
  const float invc0 = inv_n[gcol0 + wn * 64 + l31] * C;
  const float invc1 = inv_n[gcol0 + wn * 64 + 32 + l31] * C;
  const int j0 = gcol0 + wn * 64 + l31;
  const int j1 = j0 + 32;

#pragma unroll
  for (int mt = 0; mt < 4; ++mt) {
    const int ibase = grow0 + wm * 128 + mt * 32;
    float4 ir[4];
#pragma unroll
    for (int g = 0; g < 4; ++g)
      ir[g] = *(const float4*)&inv_n[ibase + g * 8 + 4 * l5];

    float rp[16];
#pragma unroll
    for (int r = 0; r < 16; ++r) {
      const int row = (r & 3) + 8 * (r >> 2) + 4 * l5;
      const int i = ibase + row;
      const float sc = ((const float*)&ir[r >> 2])[r & 3];
      float e0 = exp2f(acc[mt][0][r] * sc * invc0);
      float e1 = exp2f(acc[mt][1][r] * sc * invc1);
      if (j0 == i || j0 == i + N_ROWS) e0 = 0.0f;
      if (j1 == i || j1 == i + N_ROWS) e1 = 0.0f;
      rp[r] = e0 + e1;
    }
#pragma unroll
    for (int mk = 1; mk <= 16; mk <<= 1)
#pragma unroll
      for (int r = 0; r < 16; ++r)
        rp[r] += __shfl_xor(rp[r], mk, 32);
    if (l31 == 0) {
#pragma unroll
      for (int r = 0; r < 16; ++r)
        atomicAdd(&rowsum[ibase + (r & 3) + 8 * (r >> 2) + 4 * l5], rp[r]);
    }
  }
}

// Single block: cumsum(rowsum) -> sum(log(neg) - logpos) + sum(js) -> out[0]
__global__ __launch_bounds__(256) void final_kernel(
    const float* __restrict__ rowsum, const float* __restrict__ logpos,
    const float* __restrict__ js, float* __restrict__ out) {
  __shared__ float scan[256];
  __shared__ double ds[4];
  __shared__ float fs[4];
  const int tid = threadIdx.x;
  float loc[16];
  float run = 0.f, jl = 0.f;
#pragma unroll
  for (int k = 0; k < 16; ++k) {
    loc[k] = rowsum[tid * 16 + k];
    run += loc[k];
    jl += js[tid * 16 + k];
  }
  scan[tid] = run;
  __syncthreads();
  for (int d = 1; d < 256; d <<= 1) {
    float add = (tid >= d) ? scan[tid - d] : 0.0f;
    __syncthreads();
    scan[tid] += add;
    __syncthreads();
  }
  float c = scan[tid] - run;  // exclusive prefix
  double acc = 0.0;
#pragma unroll
  for (int k = 0; k < 16; ++k) {
    c += loc[k];
    acc += (double)(logf(c) - logpos[tid * 16 + k]);
  }
#pragma unroll
  for (int m = 32; m >= 1; m >>= 1) {
    acc += __shfl_xor(acc, m, 64);
    jl  += __shfl_xor(jl, m, 64);
  }
  if ((tid & 63) == 0) { ds[tid >> 6] = acc; fs[tid >> 6] = jl; }
  __syncthreads();
  if (tid == 0) {
    const double nce = ds[0] + ds[1] + ds[2] + ds[3];
    const double jst = (double)(fs[0] + fs[1] + fs[2] + fs[3]);
    out[0] = (float)(nce + jst / (2.0 * N_ROWS));
  }
}

extern "C" void kernel_launch(void* const* d_in, const int* in_sizes, int n_in,
                              void* d_out, int out_size, void* d_ws, size_t ws_size,
                              hipStream_t stream) {
  const float* x = (const float*)d_in[0];
  const float* y = (const float*)d_in[1];
  float* out = (float*)d_out;

  char* ws = (char*)d_ws;
  unsigned short* Bb = (unsigned short*)ws;                 // [8192][1024] bf16, 16 MB
  float* inv_n  = (float*)(ws + (size_t)16 * 1024 * 1024);  // 8192
  float* logpos = inv_n + 8192;                             // 4096
  float* rowsum = logpos + 4096;                            // 4096
  float* js     = rowsum + 4096;                            // 4096

  prep_kernel<<<N_ROWS / 4, 256, 0, stream>>>(x, y, Bb, inv_n, logpos, js, rowsum);
  gemm_fused<<<512, 512, 0, stream>>>(Bb, inv_n, rowsum);
  final_kernel<<<1, 256, 0, stream>>>(rowsum, logpos, js, out);
}

// Round 7
// 87.605 us; speedup vs baseline: 2.0250x; 2.0250x over previous
//
#include <hip/hip_runtime.h>
#include <stdint.h>

#define N_ROWS 4096
#define D_DIM  1024
#define ROWB   1024   // bytes per row in fp8
#define T_TEMP 0.15f

#define AS1 __attribute__((address_space(1)))
#define AS3 __attribute__((address_space(3)))

typedef float f32x4 __attribute__((ext_vector_type(4)));

__device__ __forceinline__ float wsum(float v) {
#pragma unroll
  for (int m = 32; m >= 1; m >>= 1) v += __shfl_xor(v, m, 64);
  return v;
}
__device__ __forceinline__ float wmax(float v) {
#pragma unroll
  for (int m = 32; m >= 1; m >>= 1) v = fmaxf(v, __shfl_xor(v, m, 64));
  return v;
}

// One WAVE per row (no barriers): norms, x.y dot (-> log pos), softmax-JS
// per-row term -> js[row], fp8-e4m3 casts into Bb = [x;y] (8192 x 1024).
// Zeroes rowsum.
__global__ __launch_bounds__(256) void prep_kernel(
    const float* __restrict__ x, const float* __restrict__ y,
    unsigned char* __restrict__ Bb, float* __restrict__ inv_n,
    float* __restrict__ logpos, float* __restrict__ js,
    float* __restrict__ rowsum) {
  if (threadIdx.x < 4) rowsum[blockIdx.x * 4 + threadIdx.x] = 0.0f;

  const int wid = threadIdx.x >> 6, lane = threadIdx.x & 63;
  const int row = blockIdx.x * 4 + wid;
  const float4* xp = (const float4*)(x + (size_t)row * D_DIM) + lane * 4;
  const float4* yp = (const float4*)(y + (size_t)row * D_DIM) + lane * 4;

  float xv[16], yv[16];
#pragma unroll
  for (int i = 0; i < 4; ++i) {
    float4 a = xp[i], b = yp[i];
    xv[i*4+0]=a.x; xv[i*4+1]=a.y; xv[i*4+2]=a.z; xv[i*4+3]=a.w;
    yv[i*4+0]=b.x; yv[i*4+1]=b.y; yv[i*4+2]=b.z; yv[i*4+3]=b.w;
  }

  float sx2=0.f, sy2=0.f, sxy=0.f, mx=-1e30f, my=-1e30f;
#pragma unroll
  for (int k = 0; k < 16; ++k) {
    sx2 = fmaf(xv[k], xv[k], sx2);
    sy2 = fmaf(yv[k], yv[k], sy2);
    sxy = fmaf(xv[k], yv[k], sxy);
    mx = fmaxf(mx, xv[k]); my = fmaxf(my, yv[k]);
  }
  sx2 = wsum(sx2); sy2 = wsum(sy2); sxy = wsum(sxy);
  mx = wmax(mx);  my = wmax(my);

  float ex[16], ey[16], sex=0.f, sey=0.f;
#pragma unroll
  for (int k = 0; k < 16; ++k) {
    ex[k] = __expf(xv[k] - mx); ey[k] = __expf(yv[k] - my);
    sex += ex[k]; sey += ey[k];
  }
  sex = wsum(sex); sey = wsum(sey);
  const float lsex = __logf(sex), lsey = __logf(sey);
  const float rsex = 1.f / sex,  rsey = 1.f / sey;

  float term = 0.f;
#pragma unroll
  for (int k = 0; k < 16; ++k) {
    float a = ex[k] * rsex, b = ey[k] * rsey;
    float lm = __logf(0.5f * (a + b));
    term += a * ((xv[k] - mx - lsex) - lm) + b * ((yv[k] - my - lsey) - lm);
  }
  term = wsum(term);

  if (lane == 0) {
    const float nx = sqrtf(sx2), ny = sqrtf(sy2);
    inv_n[row] = 1.f / nx;
    inv_n[N_ROWS + row] = 1.f / ny;
    logpos[row] = sxy / fmaxf(nx * ny, 1e-8f) / T_TEMP;  // ln(pos)
    js[row] = term;
  }

  int p[4], q[4];
#pragma unroll
  for (int w = 0; w < 4; ++w) {
    int v = 0;
    v = __builtin_amdgcn_cvt_pk_fp8_f32(xv[w*4+0], xv[w*4+1], v, false);
    v = __builtin_amdgcn_cvt_pk_fp8_f32(xv[w*4+2], xv[w*4+3], v, true);
    p[w] = v;
    int u = 0;
    u = __builtin_amdgcn_cvt_pk_fp8_f32(yv[w*4+0], yv[w*4+1], u, false);
    u = __builtin_amdgcn_cvt_pk_fp8_f32(yv[w*4+2], yv[w*4+3], u, true);
    q[w] = u;
  }
  *(int4*)(Bb + (size_t)row * ROWB + lane * 16) = make_int4(p[0], p[1], p[2], p[3]);
  *(int4*)(Bb + (size_t)(N_ROWS + row) * ROWB + lane * 16) = make_int4(q[0], q[1], q[2], q[3]);
}

// ===== fp8 symmetric fused GEMM, 128x128 tile, 4 waves, BK=64 =====
// A = rows [0,4096) of Bb (=x), B = all 8192 rows (=[x;y]).
// idx<1024 -> Sxy tile (bi, 32+bj'); else upper-triangle Sxx tile (bi<=bj);
// sym tiles also add col-sums (Sxx symmetric).
// LDS k-step-major [kk][128][32B]: every GLL (4KB/call) and every
// ds_read_b64 is wave-dense lane-linear (the only pattern measured
// conflict-free in R1-R6). 16 K-tiles x 2 barriers = 32 barriers.
#define GLL(src, dst) __builtin_amdgcn_global_load_lds((const AS1 void*)(src), (AS3 void*)(dst), 16, 0, 0)

__global__ __launch_bounds__(256, 3) void gemm_fused(
    const unsigned char* __restrict__ Bb, const float* __restrict__ inv_n,
    float* __restrict__ rowsum) {
  __shared__ __align__(16) char As[2 * 4096];   // [kk][128][32]
  __shared__ __align__(16) char Bs[2 * 4096];
  const int tid = threadIdx.x;
  const int wid = tid >> 6, lane = tid & 63;
  const int lo = lane & 15, hi = lane >> 4;

  int bi, bj;
  bool sym = false;
  {
    const int idx = blockIdx.x;
    if (idx < 1024) {
      bi = idx >> 5; bj = 32 + (idx & 31);
    } else {
      const int t = idx - 1024;
      int b = (int)((65.0 - sqrt((double)(4225 - 8 * t))) * 0.5);
      while ((b + 1) * (65 - (b + 1)) / 2 <= t) ++b;
      while (b * (65 - b) / 2 > t) --b;
      bi = b;
      bj = b + (t - b * (65 - b) / 2);
      sym = (bi != bj);
    }
  }
  const int grow0 = bi * 128;
  const int gcol0 = bj * 128;
  const int wrow = (wid >> 1) * 64, wcol = (wid & 1) * 64;

  f32x4 acc[4][4] = {};

  // staging: thread t covers row t>>1, 16B-half t&1 of a [128][32B] k-step
  // plane; LDS dest = plane + t*16 (lane-linear), global src contiguous 16B.
  const char* gA = (const char*)Bb + (size_t)(grow0 + (tid >> 1)) * ROWB + (tid & 1) * 16;
  const char* gB = (const char*)Bb + (size_t)(gcol0 + (tid >> 1)) * ROWB + (tid & 1) * 16;
  char* dA = As + tid * 16;
  char* dB = Bs + tid * 16;

  // fragment bases: lane (lo,hi) reads 8B at row*32 + hi*8 (dense 512B/tile)
  const char* lA = As + lo * 32 + hi * 8;
  const char* lB = Bs + lo * 32 + hi * 8;

  for (int kt = 0; kt < 16; ++kt) {
    __syncthreads();   // prior reads done before overwrite
    GLL(gA + kt * 64,      dA);          // A kk0
    GLL(gA + kt * 64 + 32, dA + 4096);   // A kk1
    GLL(gB + kt * 64,      dB);          // B kk0
    GLL(gB + kt * 64 + 32, dB + 4096);   // B kk1
    __syncthreads();   // staging visible

    long a[4], b[4];
#pragma unroll
    for (int kk = 0; kk < 2; ++kk) {
#pragma unroll
      for (int m = 0; m < 4; ++m)
        a[m] = *(const long*)(lA + kk * 4096 + (wrow + m * 16) * 32);
#pragma unroll
      for (int n = 0; n < 4; ++n)
        b[n] = *(const long*)(lB + kk * 4096 + (wcol + n * 16) * 32);
#pragma unroll
      for (int m = 0; m < 4; ++m)
#pragma unroll
        for (int n = 0; n < 4; ++n)
          acc[m][n] = __builtin_amdgcn_mfma_f32_16x16x32_fp8_fp8(
              a[m], b[n], acc[m][n], 0, 0, 0);
    }
  }

  // epilogue: scale -> exp2 -> mask diag -> row-reduce (+col-reduce if sym)
  const float C = 1.4426950408889634f / T_TEMP;   // log2(e)/T
  float invc[4], invr[4][4];
#pragma unroll
  for (int n = 0; n < 4; ++n)
    invc[n] = inv_n[gcol0 + wcol + n * 16 + lo] * C;
#pragma unroll
  for (int m = 0; m < 4; ++m)
#pragma unroll
    for (int r = 0; r < 4; ++r)
      invr[m][r] = inv_n[grow0 + wrow + m * 16 + hi * 4 + r];

  float rp[4][4] = {};
  float cp[4] = {};
#pragma unroll
  for (int m = 0; m < 4; ++m)
#pragma unroll
    for (int n = 0; n < 4; ++n)
#pragma unroll
      for (int r = 0; r < 4; ++r) {
        const int i = grow0 + wrow + m * 16 + hi * 4 + r;
        const int j = gcol0 + wcol + n * 16 + lo;
        float e2 = exp2f(acc[m][n][r] * invr[m][r] * invc[n]);
        if (j == i || j == i + N_ROWS) e2 = 0.0f;
        rp[m][r] += e2;
        cp[n] += e2;
      }

#pragma unroll
  for (int m = 0; m < 4; ++m)
#pragma unroll
    for (int r = 0; r < 4; ++r) {
      float v = rp[m][r];
      v += __shfl_xor(v, 1, 16);
      v += __shfl_xor(v, 2, 16);
      v += __shfl_xor(v, 4, 16);
      v += __shfl_xor(v, 8, 16);
      if (lo == 0)
        atomicAdd(&rowsum[grow0 + wrow + m * 16 + hi * 4 + r], v);
    }

  if (sym) {
#pragma unroll
    for (int n = 0; n < 4; ++n) {
      float v = cp[n];
      v += __shfl_xor(v, 16, 64);
      v += __shfl_xor(v, 32, 64);
      if (hi == 0)
        atomicAdd(&rowsum[gcol0 + wcol + n * 16 + lo], v);
    }
  }
}

// Single block: cumsum(rowsum) -> sum(log(neg) - logpos) + sum(js) -> out[0]
__global__ __launch_bounds__(256) void final_kernel(
    const float* __restrict__ rowsum, const float* __restrict__ logpos,
    const float* __restrict__ js, float* __restrict__ out) {
  __shared__ float scan[256];
  __shared__ double ds[4];
  __shared__ float fs[4];
  const int tid = threadIdx.x;
  float loc[16];
  float run = 0.f, jl = 0.f;
#pragma unroll
  for (int k = 0; k < 16; ++k) {
    loc[k] = rowsum[tid * 16 + k];
    run += loc[k];
    jl += js[tid * 16 + k];
  }
  scan[tid] = run;
  __syncthreads();
  for (int d = 1; d < 256; d <<= 1) {
    float add = (tid >= d) ? scan[tid - d] : 0.0f;
    __syncthreads();
    scan[tid] += add;
    __syncthreads();
  }
  float c = scan[tid] - run;  // exclusive prefix
  double acc = 0.0;
#pragma unroll
  for (int k = 0; k < 16; ++k) {
    c += loc[k];
    acc += (double)(logf(c) - logpos[tid * 16 + k]);
  }
#pragma unroll
  for (int m = 32; m >= 1; m >>= 1) {
    acc += __shfl_xor(acc, m, 64);
    jl  += __shfl_xor(jl, m, 64);
  }
  if ((tid & 63) == 0) { ds[tid >> 6] = acc; fs[tid >> 6] = jl; }
  __syncthreads();
  if (tid == 0) {
    const double nce = ds[0] + ds[1] + ds[2] + ds[3];
    const double jst = (double)(fs[0] + fs[1] + fs[2] + fs[3]);
    out[0] = (float)(nce + jst / (2.0 * N_ROWS));
  }
}

extern "C" void kernel_launch(void* const* d_in, const int* in_sizes, int n_in,
                              void* d_out, int out_size, void* d_ws, size_t ws_size,
                              hipStream_t stream) {
  const float* x = (const float*)d_in[0];
  const float* y = (const float*)d_in[1];
  float* out = (float*)d_out;

  char* ws = (char*)d_ws;
  unsigned char* Bb = (unsigned char*)ws;                  // [8192][1024] fp8, 8 MB
  float* inv_n  = (float*)(ws + (size_t)8 * 1024 * 1024);  // 8192
  float* logpos = inv_n + 8192;                            // 4096
  float* rowsum = logpos + 4096;                           // 4096
  float* js     = rowsum + 4096;                           // 4096

  prep_kernel<<<N_ROWS / 4, 256, 0, stream>>>(x, y, Bb, inv_n, logpos, js, rowsum);
  gemm_fused<<<1552, 256, 0, stream>>>(Bb, inv_n, rowsum);
  final_kernel<<<1, 256, 0, stream>>>(rowsum, logpos, js, out);
}

// Round 8
// 75.151 us; speedup vs baseline: 2.3606x; 1.1657x over previous
//
#include <hip/hip_runtime.h>
#include <stdint.h>

#define N_ROWS 4096
#define D_DIM  1024
#define ROWB   1024   // bytes per row in fp8
#define T_TEMP 0.15f

#define AS1 __attribute__((address_space(1)))
#define AS3 __attribute__((address_space(3)))

typedef float f32x4 __attribute__((ext_vector_type(4)));

__device__ __forceinline__ float wsum(float v) {
#pragma unroll
  for (int m = 32; m >= 1; m >>= 1) v += __shfl_xor(v, m, 64);
  return v;
}
__device__ __forceinline__ float wmax(float v) {
#pragma unroll
  for (int m = 32; m >= 1; m >>= 1) v = fmaxf(v, __shfl_xor(v, m, 64));
  return v;
}

// One WAVE per row (no barriers): norms, x.y dot (-> log pos), softmax-JS
// per-row term -> js[row], fp8-e4m3 casts into Bb = [x;y] (8192 x 1024).
// Zeroes rowsum.
__global__ __launch_bounds__(256) void prep_kernel(
    const float* __restrict__ x, const float* __restrict__ y,
    unsigned char* __restrict__ Bb, float* __restrict__ inv_n,
    float* __restrict__ logpos, float* __restrict__ js,
    float* __restrict__ rowsum) {
  if (threadIdx.x < 4) rowsum[blockIdx.x * 4 + threadIdx.x] = 0.0f;

  const int wid = threadIdx.x >> 6, lane = threadIdx.x & 63;
  const int row = blockIdx.x * 4 + wid;
  const float4* xp = (const float4*)(x + (size_t)row * D_DIM) + lane * 4;
  const float4* yp = (const float4*)(y + (size_t)row * D_DIM) + lane * 4;

  float xv[16], yv[16];
#pragma unroll
  for (int i = 0; i < 4; ++i) {
    float4 a = xp[i], b = yp[i];
    xv[i*4+0]=a.x; xv[i*4+1]=a.y; xv[i*4+2]=a.z; xv[i*4+3]=a.w;
    yv[i*4+0]=b.x; yv[i*4+1]=b.y; yv[i*4+2]=b.z; yv[i*4+3]=b.w;
  }

  float sx2=0.f, sy2=0.f, sxy=0.f, mx=-1e30f, my=-1e30f;
#pragma unroll
  for (int k = 0; k < 16; ++k) {
    sx2 = fmaf(xv[k], xv[k], sx2);
    sy2 = fmaf(yv[k], yv[k], sy2);
    sxy = fmaf(xv[k], yv[k], sxy);
    mx = fmaxf(mx, xv[k]); my = fmaxf(my, yv[k]);
  }
  sx2 = wsum(sx2); sy2 = wsum(sy2); sxy = wsum(sxy);
  mx = wmax(mx);  my = wmax(my);

  float ex[16], ey[16], sex=0.f, sey=0.f;
#pragma unroll
  for (int k = 0; k < 16; ++k) {
    ex[k] = __expf(xv[k] - mx); ey[k] = __expf(yv[k] - my);
    sex += ex[k]; sey += ey[k];
  }
  sex = wsum(sex); sey = wsum(sey);
  const float lsex = __logf(sex), lsey = __logf(sey);
  const float rsex = 1.f / sex,  rsey = 1.f / sey;

  float term = 0.f;
#pragma unroll
  for (int k = 0; k < 16; ++k) {
    float a = ex[k] * rsex, b = ey[k] * rsey;
    float lm = __logf(0.5f * (a + b));
    term += a * ((xv[k] - mx - lsex) - lm) + b * ((yv[k] - my - lsey) - lm);
  }
  term = wsum(term);

  if (lane == 0) {
    const float nx = sqrtf(sx2), ny = sqrtf(sy2);
    inv_n[row] = 1.f / nx;
    inv_n[N_ROWS + row] = 1.f / ny;
    logpos[row] = sxy / fmaxf(nx * ny, 1e-8f) / T_TEMP;  // ln(pos)
    js[row] = term;
  }

  int p[4], q[4];
#pragma unroll
  for (int w = 0; w < 4; ++w) {
    int v = 0;
    v = __builtin_amdgcn_cvt_pk_fp8_f32(xv[w*4+0], xv[w*4+1], v, false);
    v = __builtin_amdgcn_cvt_pk_fp8_f32(xv[w*4+2], xv[w*4+3], v, true);
    p[w] = v;
    int u = 0;
    u = __builtin_amdgcn_cvt_pk_fp8_f32(yv[w*4+0], yv[w*4+1], u, false);
    u = __builtin_amdgcn_cvt_pk_fp8_f32(yv[w*4+2], yv[w*4+3], u, true);
    q[w] = u;
  }
  *(int4*)(Bb + (size_t)row * ROWB + lane * 16) = make_int4(p[0], p[1], p[2], p[3]);
  *(int4*)(Bb + (size_t)(N_ROWS + row) * ROWB + lane * 16) = make_int4(q[0], q[1], q[2], q[3]);
}

// ===== fp8 symmetric fused GEMM, 128x128 tile, 4 waves, BK=64 =====
// A = rows [0,4096) of Bb (=x), B = all 8192 rows (=[x;y]).
// idx<1024 -> Sxy tile; else upper-triangle Sxx tile (col-sums added too).
// LDS k-step-major [kk][128 rows][32B]. 8B-slot s of row r holds global
// chunk s ^ 2*((r>>2)&1)  (both-sides swizzle: staging pre-swizzles the
// global 16B chunk-pair by (r>>2)&1; reader XORs the same). This turns the
// R7-measured 4-way b64 bank alias (19M conflict-cycles) into 2-way (free).
#define GLL(src, dst) __builtin_amdgcn_global_load_lds((const AS1 void*)(src), (AS3 void*)(dst), 16, 0, 0)

__global__ __launch_bounds__(256, 3) void gemm_fused(
    const unsigned char* __restrict__ Bb, const float* __restrict__ inv_n,
    float* __restrict__ rowsum) {
  __shared__ __align__(16) char As[2 * 4096];   // [kk][128][32]
  __shared__ __align__(16) char Bs[2 * 4096];
  const int tid = threadIdx.x;
  const int wid = tid >> 6, lane = tid & 63;
  const int lo = lane & 15, hi = lane >> 4;

  int bi, bj;
  bool sym = false;
  {
    const int idx = blockIdx.x;
    if (idx < 1024) {
      bi = idx >> 5; bj = 32 + (idx & 31);
    } else {
      const int t = idx - 1024;
      int b = (int)((65.0 - sqrt((double)(4225 - 8 * t))) * 0.5);
      while ((b + 1) * (65 - (b + 1)) / 2 <= t) ++b;
      while (b * (65 - b) / 2 > t) --b;
      bi = b;
      bj = b + (t - b * (65 - b) / 2);
      sym = (bi != bj);
    }
  }
  const int grow0 = bi * 128;
  const int gcol0 = bj * 128;
  const int wrow = (wid >> 1) * 64, wcol = (wid & 1) * 64;

  f32x4 acc[4][4] = {};

  // staging: thread t covers row t>>1; its 16B chunk-pair within each 32B
  // kk-slice is pre-swizzled: cp = (t&1) ^ ((row>>2)&1) = (t&1) ^ ((t>>3)&1).
  // LDS dest stays dense t*16.
  const int scp = (tid & 1) ^ ((tid >> 3) & 1);
  const char* gA = (const char*)Bb + (size_t)(grow0 + (tid >> 1)) * ROWB + scp * 16;
  const char* gB = (const char*)Bb + (size_t)(gcol0 + (tid >> 1)) * ROWB + scp * 16;
  char* dA = As + tid * 16;
  char* dB = Bs + tid * 16;

  // fragment bases: lane (lo,hi) reads 8B slot hi ^ 2*((lo>>2)&1) of row lo
  // (bank-pair p = 4*(lo&3) + slot -> 8 pairs x 2 lanes = 2-way, free)
  const int slot = hi ^ (((lo >> 2) & 1) << 1);
  const char* lA = As + lo * 32 + slot * 8;
  const char* lB = Bs + lo * 32 + slot * 8;

  for (int kt = 0; kt < 16; ++kt) {
    __syncthreads();   // prior reads done before overwrite
    GLL(gA + kt * 64,      dA);          // A kk0
    GLL(gA + kt * 64 + 32, dA + 4096);   // A kk1
    GLL(gB + kt * 64,      dB);          // B kk0
    GLL(gB + kt * 64 + 32, dB + 4096);   // B kk1
    __syncthreads();   // staging visible

    long a[4], b[4];
#pragma unroll
    for (int kk = 0; kk < 2; ++kk) {
#pragma unroll
      for (int m = 0; m < 4; ++m)
        a[m] = *(const long*)(lA + kk * 4096 + (wrow + m * 16) * 32);
#pragma unroll
      for (int n = 0; n < 4; ++n)
        b[n] = *(const long*)(lB + kk * 4096 + (wcol + n * 16) * 32);
#pragma unroll
      for (int m = 0; m < 4; ++m)
#pragma unroll
        for (int n = 0; n < 4; ++n)
          acc[m][n] = __builtin_amdgcn_mfma_f32_16x16x32_fp8_fp8(
              a[m], b[n], acc[m][n], 0, 0, 0);
    }
  }

  // epilogue: scale -> exp2 -> mask diag -> row-reduce (+col-reduce if sym)
  const float C = 1.4426950408889634f / T_TEMP;   // log2(e)/T
  float invc[4], invr[4][4];
#pragma unroll
  for (int n = 0; n < 4; ++n)
    invc[n] = inv_n[gcol0 + wcol + n * 16 + lo] * C;
#pragma unroll
  for (int m = 0; m < 4; ++m)
#pragma unroll
    for (int r = 0; r < 4; ++r)
      invr[m][r] = inv_n[grow0 + wrow + m * 16 + hi * 4 + r];

  float rp[4][4] = {};
  float cp[4] = {};
#pragma unroll
  for (int m = 0; m < 4; ++m)
#pragma unroll
    for (int n = 0; n < 4; ++n)
#pragma unroll
      for (int r = 0; r < 4; ++r) {
        const int i = grow0 + wrow + m * 16 + hi * 4 + r;
        const int j = gcol0 + wcol + n * 16 + lo;
        float e2 = exp2f(acc[m][n][r] * invr[m][r] * invc[n]);
        if (j == i || j == i + N_ROWS) e2 = 0.0f;
        rp[m][r] += e2;
        cp[n] += e2;
      }

#pragma unroll
  for (int m = 0; m < 4; ++m)
#pragma unroll
    for (int r = 0; r < 4; ++r) {
      float v = rp[m][r];
      v += __shfl_xor(v, 1, 16);
      v += __shfl_xor(v, 2, 16);
      v += __shfl_xor(v, 4, 16);
      v += __shfl_xor(v, 8, 16);
      if (lo == 0)
        atomicAdd(&rowsum[grow0 + wrow + m * 16 + hi * 4 + r], v);
    }

  if (sym) {
#pragma unroll
    for (int n = 0; n < 4; ++n) {
      float v = cp[n];
      v += __shfl_xor(v, 16, 64);
      v += __shfl_xor(v, 32, 64);
      if (hi == 0)
        atomicAdd(&rowsum[gcol0 + wcol + n * 16 + lo], v);
    }
  }
}

// Single block: cumsum(rowsum) -> sum(log(neg) - logpos) + sum(js) -> out[0]
__global__ __launch_bounds__(256) void final_kernel(
    const float* __restrict__ rowsum, const float* __restrict__ logpos,
    const float* __restrict__ js, float* __restrict__ out) {
  __shared__ float scan[256];
  __shared__ double ds[4];
  __shared__ float fs[4];
  const int tid = threadIdx.x;
  float loc[16];
  float run = 0.f, jl = 0.f;
#pragma unroll
  for (int k = 0; k < 16; ++k) {
    loc[k] = rowsum[tid * 16 + k];
    run += loc[k];
    jl += js[tid * 16 + k];
  }
  scan[tid] = run;
  __syncthreads();
  for (int d = 1; d < 256; d <<= 1) {
    float add = (tid >= d) ? scan[tid - d] : 0.0f;
    __syncthreads();
    scan[tid] += add;
    __syncthreads();
  }
  float c = scan[tid] - run;  // exclusive prefix
  double acc = 0.0;
#pragma unroll
  for (int k = 0; k < 16; ++k) {
    c += loc[k];
    acc += (double)(logf(c) - logpos[tid * 16 + k]);
  }
#pragma unroll
  for (int m = 32; m >= 1; m >>= 1) {
    acc += __shfl_xor(acc, m, 64);
    jl  += __shfl_xor(jl, m, 64);
  }
  if ((tid & 63) == 0) { ds[tid >> 6] = acc; fs[tid >> 6] = jl; }
  __syncthreads();
  if (tid == 0) {
    const double nce = ds[0] + ds[1] + ds[2] + ds[3];
    const double jst = (double)(fs[0] + fs[1] + fs[2] + fs[3]);
    out[0] = (float)(nce + jst / (2.0 * N_ROWS));
  }
}

extern "C" void kernel_launch(void* const* d_in, const int* in_sizes, int n_in,
                              void* d_out, int out_size, void* d_ws, size_t ws_size,
                              hipStream_t stream) {
  const float* x = (const float*)d_in[0];
  const float* y = (const float*)d_in[1];
  float* out = (float*)d_out;

  char* ws = (char*)d_ws;
  unsigned char* Bb = (unsigned char*)ws;                  // [8192][1024] fp8, 8 MB
  float* inv_n  = (float*)(ws + (size_t)8 * 1024 * 1024);  // 8192
  float* logpos = inv_n + 8192;                            // 4096
  float* rowsum = logpos + 4096;                           // 4096
  float* js     = rowsum + 4096;                           // 4096

  prep_kernel<<<N_ROWS / 4, 256, 0, stream>>>(x, y, Bb, inv_n, logpos, js, rowsum);
  gemm_fused<<<1552, 256, 0, stream>>>(Bb, inv_n, rowsum);
  final_kernel<<<1, 256, 0, stream>>>(rowsum, logpos, js, out);
}